// Round 1
// baseline (163.598 us; speedup 1.0000x reference)
//
#include <hip/hip_runtime.h>

#define NN 100000
#define NE 1000000
#define OUT_D 64
#define EPS 1e-5f

#define NB 196          // buckets of 512 destination cols: 196*512 = 100352 >= NN
#define COLS 512
#define BSTRIDE 6016    // per-bucket raw capacity: mean 5120, +12.6 sigma
#define EPB 4096        // edges per part-block
#define NBLK1 245       // part blocks = ceil(NE/EPB)
#define NPROJ 1024      // proj blocks fused behind part

#define QCOLS 128       // cols per agg block (bucket quarter)
#define QCAP 2560       // padded per-quarter capacity: mean 1280+pads<=384, +25 sigma

typedef __attribute__((ext_vector_type(8))) short bf16x8;
typedef __attribute__((ext_vector_type(4))) float f32x4;
typedef __attribute__((ext_vector_type(4))) int i32x4;

static __device__ __forceinline__ unsigned short f2bf(float f) {   // RNE
    unsigned u = __float_as_uint(f);
    u += 0x7FFFu + ((u >> 16) & 1u);
    return (unsigned short)(u >> 16);
}
static __device__ __forceinline__ float bf2f(unsigned short s) {
    return __uint_as_float((unsigned)s << 16);
}

// ---- mega kernel: blocks [0,NBLK1) partition edges; [NBLK1,..) do MFMA proj
__global__ __launch_bounds__(256) void mega_kernel(
    const float* __restrict__ x, const float* __restrict__ W,
    const int* __restrict__ ei, int* __restrict__ gcur, unsigned* __restrict__ gbuf,
    unsigned short* __restrict__ y1, unsigned short* __restrict__ y2)
{
    const int tid = threadIdx.x;
    const int lane = tid & 63;
    const int wv = tid >> 6;

    if (blockIdx.x < NBLK1) {
        // ---------------- partition by dst-bucket (LDS-staged) ----------------
        __shared__ int lcnt[NB];
        __shared__ int loff[NB + 1];
        __shared__ int lbase[NB];
        __shared__ int lcur[NB];
        __shared__ int wpart[4];
        __shared__ unsigned lbuf[EPB];
        __shared__ unsigned char lbkt[EPB];
        const int e0 = blockIdx.x * EPB;

        int rows[16], cols[16];
        #pragma unroll
        for (int j = 0; j < 16; ++j) {
            const int e = e0 + j * 256 + tid;
            const bool v = e < NE;
            rows[j] = v ? ei[e] : 0;
            cols[j] = v ? ei[NE + e] : -1;
        }
        for (int i = tid; i < NB; i += 256) lcnt[i] = 0;
        __syncthreads();
        #pragma unroll
        for (int j = 0; j < 16; ++j)
            if (cols[j] >= 0) atomicAdd(&lcnt[cols[j] >> 9], 1);
        __syncthreads();
        {   // block exclusive scan over NB bucket counts
            const int c = (tid < NB) ? lcnt[tid] : 0;
            int s = c;
            #pragma unroll
            for (int o = 1; o < 64; o <<= 1) { int t = __shfl_up(s, o); if (lane >= o) s += t; }
            if (lane == 63) wpart[wv] = s;
            __syncthreads();
            int woff = 0;
            for (int ww = 0; ww < wv; ++ww) woff += wpart[ww];
            if (tid < NB) {
                loff[tid] = woff + s - c;
                lcur[tid] = woff + s - c;
                lbase[tid] = atomicAdd(&gcur[tid], c);
            }
            if (tid == NB - 1) loff[NB] = woff + s;
        }
        __syncthreads();
        #pragma unroll
        for (int j = 0; j < 16; ++j) {
            if (cols[j] >= 0) {
                const int b = cols[j] >> 9;
                const int p = atomicAdd(&lcur[b], 1);
                lbuf[p] = ((unsigned)rows[j] << 9) | (unsigned)(cols[j] & (COLS - 1));
                lbkt[p] = (unsigned char)b;
            }
        }
        __syncthreads();
        const int total = loff[NB];
        for (int t = tid; t < total; t += 256) {   // ~21-word coalesced bursts
            const int b = lbkt[t];
            const unsigned idx = (unsigned)(lbase[b] + (t - loff[b]));
            if (idx < BSTRIDE) gbuf[(size_t)b * BSTRIDE + idx] = lbuf[t];
        }
    } else {
        // ---------------- [y1|y2] = x @ [W1|W2] via MFMA (m89 layouts) --------
        if (blockIdx.x == NBLK1 && tid < OUT_D)
            y2[(size_t)NN * OUT_D + tid] = 0;   // zeros row for pad gathers
        const int m = lane & 15;
        const int quad = lane >> 4;
        bf16x8 Wf[8][2];
        #pragma unroll
        for (int t = 0; t < 8; ++t)
            #pragma unroll
            for (int q = 0; q < 2; ++q) {
                bf16x8 f;
                #pragma unroll
                for (int j = 0; j < 8; ++j) {
                    const int k = q * 32 + quad * 8 + j;
                    const int krow = (t < 4) ? k : (64 + k);
                    const int col = (t & 3) * 16 + m;
                    f[j] = (short)f2bf(W[krow * 64 + col]);
                }
                Wf[t][q] = f;
            }
        for (int tile = (blockIdx.x - NBLK1) * 4 + wv; tile < NN / 16; tile += NPROJ * 4) {
            const int n0 = tile * 16;
            bf16x8 Af[2];
            #pragma unroll
            for (int q = 0; q < 2; ++q) {
                const float* px = x + (size_t)(n0 + m) * 64 + q * 32 + quad * 8;
                const f32x4 a0 = *(const f32x4*)px;
                const f32x4 a1 = *(const f32x4*)(px + 4);
                bf16x8 f;
                #pragma unroll
                for (int j = 0; j < 4; ++j) { f[j] = (short)f2bf(a0[j]); f[4 + j] = (short)f2bf(a1[j]); }
                Af[q] = f;
            }
            #pragma unroll
            for (int t = 0; t < 8; ++t) {
                f32x4 acc = {0.f, 0.f, 0.f, 0.f};
                acc = __builtin_amdgcn_mfma_f32_16x16x32_bf16(Af[0], Wf[t][0], acc, 0, 0, 0);
                acc = __builtin_amdgcn_mfma_f32_16x16x32_bf16(Af[1], Wf[t][1], acc, 0, 0, 0);
                unsigned short* __restrict__ dst = (t < 4) ? y1 : y2;
                const int colb = (t & 3) * 16 + m;
                #pragma unroll
                for (int r = 0; r < 4; ++r)
                    dst[(size_t)(n0 + quad * 4 + r) * 64 + colb] = f2bf(acc[r]);
            }
        }
    }
}

// ---- fused CSR-build + gather + LN: one block per bucket-quarter ----------
// Phase A: two-pass stream of the bucket's gbuf segment -> padded per-col
//          neighbor lists in LDS (pads -> row NN = zeros).
// Phase B: per node (wave-uniform): 8 gathers in flight from y2, add y1+bias,
//          LayerNorm, store. Neighbor lists read from LDS (broadcast b128).
__global__ __launch_bounds__(256) void agg_kernel(
    const int* __restrict__ gcur, const unsigned* __restrict__ gbuf,
    const unsigned short* __restrict__ y1, const unsigned short* __restrict__ y2,
    const float* __restrict__ bias, const float* __restrict__ gamma,
    const float* __restrict__ beta, float* __restrict__ out)
{
    __shared__ int cofs[QCOLS + 1];   // padded exclusive scan (inclusive at end)
    __shared__ int ccur[QCOLS];
    __shared__ int ccnt[QCOLS];
    __shared__ int ldst[QCAP];
    const int tid = threadIdx.x;
    const int lane = tid & 63;
    const int wv = tid >> 6;
    const int b = blockIdx.x >> 2;        // bucket
    const int q = blockIdx.x & 3;         // quarter within bucket

    const int cntE = min(gcur[b], BSTRIDE);
    const unsigned* __restrict__ gb = gbuf + (size_t)b * BSTRIDE;

    for (int i = tid; i < QCOLS; i += 256) ccnt[i] = 0;
    for (int i = tid; i < QCAP; i += 256) ldst[i] = NN;   // pad = zeros row
    __syncthreads();
    for (int i = tid; i < cntE; i += 256) {               // pass 1: histogram
        const unsigned p = gb[i];
        const unsigned c9 = p & 511u;
        if ((int)(c9 >> 7) == q) atomicAdd(&ccnt[c9 & (QCOLS - 1)], 1);
    }
    __syncthreads();
    if (tid < 64) {   // single-wave exclusive scan of 128 PADDED counts (2/lane)
        int v0 = (ccnt[2 * tid] + 3) & ~3;
        int v1 = (ccnt[2 * tid + 1] + 3) & ~3;
        const int tsum = v0 + v1;
        int s = tsum;
        #pragma unroll
        for (int o = 1; o < 64; o <<= 1) { int t = __shfl_up(s, o); if (tid >= o) s += t; }
        int run = s - tsum;
        cofs[2 * tid] = run;     ccur[2 * tid] = run;     run += v0;
        cofs[2 * tid + 1] = run; ccur[2 * tid + 1] = run; run += v1;
        if (tid == 63) cofs[QCOLS] = run;
    }
    __syncthreads();
    for (int i = tid; i < cntE; i += 256) {               // pass 2: scatter
        const unsigned p = gb[i];
        const unsigned c9 = p & 511u;
        if ((int)(c9 >> 7) == q) {
            const int pos = atomicAdd(&ccur[c9 & (QCOLS - 1)], 1);
            if (pos < QCAP) ldst[pos] = (int)(p >> 9);
        }
    }
    __syncthreads();

    const int n0 = (b << 9) + (q << 7);
    for (int cl = wv; cl < QCOLS; cl += 4) {              // one node per wave
        const int n = n0 + cl;
        if (n >= NN) continue;                            // tail bucket guard
        const int st = min(cofs[cl], QCAP);               // multiples of 4
        const int en = min(cofs[cl + 1], QCAP);
        const int cnt = en - st;
        const int* __restrict__ cp = ldst + st;

        float acc = bf2f(y1[(size_t)n * OUT_D + lane]) + bias[lane];
        int i = 0;
        for (; i + 8 <= cnt; i += 8) {                    // 8 gathers in flight
            const i32x4 c0 = *(const i32x4*)(cp + i);
            const i32x4 c1 = *(const i32x4*)(cp + i + 4);
            const float v0 = bf2f(y2[(size_t)c0[0] * OUT_D + lane]);
            const float v1 = bf2f(y2[(size_t)c0[1] * OUT_D + lane]);
            const float v2 = bf2f(y2[(size_t)c0[2] * OUT_D + lane]);
            const float v3 = bf2f(y2[(size_t)c0[3] * OUT_D + lane]);
            const float v4 = bf2f(y2[(size_t)c1[0] * OUT_D + lane]);
            const float v5 = bf2f(y2[(size_t)c1[1] * OUT_D + lane]);
            const float v6 = bf2f(y2[(size_t)c1[2] * OUT_D + lane]);
            const float v7 = bf2f(y2[(size_t)c1[3] * OUT_D + lane]);
            acc += ((v0 + v1) + (v2 + v3)) + ((v4 + v5) + (v6 + v7));
        }
        if (i < cnt) {                                    // exactly 4 left
            const i32x4 c0 = *(const i32x4*)(cp + i);
            const float v0 = bf2f(y2[(size_t)c0[0] * OUT_D + lane]);
            const float v1 = bf2f(y2[(size_t)c0[1] * OUT_D + lane]);
            const float v2 = bf2f(y2[(size_t)c0[2] * OUT_D + lane]);
            const float v3 = bf2f(y2[(size_t)c0[3] * OUT_D + lane]);
            acc += (v0 + v1) + (v2 + v3);
        }

        float sv = acc, sq = acc * acc;
        #pragma unroll
        for (int off = 32; off; off >>= 1) { sv += __shfl_xor(sv, off); sq += __shfl_xor(sq, off); }
        const float mu  = sv * (1.0f / OUT_D);
        const float var = sq * (1.0f / OUT_D) - mu * mu;
        const float inv = rsqrtf(var + EPS);
        out[(size_t)n * OUT_D + lane] = (acc - mu) * inv * gamma[lane] + beta[lane];
    }
}

extern "C" void kernel_launch(void* const* d_in, const int* in_sizes, int n_in,
                              void* d_out, int out_size, void* d_ws, size_t ws_size,
                              hipStream_t stream) {
    const float* x     = (const float*)d_in[0];
    const int*   ei    = (const int*)  d_in[1];
    const float* W     = (const float*)d_in[2];
    const float* b     = (const float*)d_in[3];
    const float* gamma = (const float*)d_in[4];
    const float* beta  = (const float*)d_in[5];
    float* out = (float*)d_out;

    char* p = (char*)d_ws;
    int*            gcur    = (int*)p;             p += 1024;
    unsigned*       gbuf    = (unsigned*)p;        p += (size_t)NB * BSTRIDE * 4;   // 4.72 MB
    unsigned short* y1      = (unsigned short*)p;  p += (size_t)NN * OUT_D * 2;     // 12.8 MB
    unsigned short* y2      = (unsigned short*)p;                                   // 12.8 MB + zero row

    hipMemsetAsync(gcur, 0, NB * sizeof(int), stream);
    mega_kernel<<<NBLK1 + NPROJ, 256, 0, stream>>>(x, W, ei, gcur, gbuf, y1, y2);
    agg_kernel <<<NB * 4,        256, 0, stream>>>(gcur, gbuf, y1, y2, b, gamma, beta, out);
}